// Round 7
// baseline (116.092 us; speedup 1.0000x reference)
//
#include <hip/hip_runtime.h>
#include <hip/hip_bf16.h>

#define N_NODES 50000
#define N_EDGES 500000
#define IN_FEATS 96
#define OUT_FEATS 128
#define N_ETYPES 4
#define KCAT (N_ETYPES * IN_FEATS)  // 384

typedef __attribute__((ext_vector_type(8))) short short8;
typedef __attribute__((ext_vector_type(4))) float f32x4;

static __device__ inline short f2bf_bits(float f) {
    __hip_bfloat16 h = __float2bfloat16(f);
    return *reinterpret_cast<short*>(&h);
}
static __device__ inline unsigned pack2bf(float lo, float hi) {
    unsigned l = (unsigned short)f2bf_bits(lo);
    unsigned h = (unsigned short)f2bf_bits(hi);
    return l | (h << 16);
}

// ---------------------------------------------------------------------------
// k_init: zero deg[] AND pre-convert W (f32 [4][128][128], first 96 cols) to
// bf16 Wb [4*128][96] (stored as u32 pairs).
// ---------------------------------------------------------------------------
__global__ __launch_bounds__(256) void k_init(int* __restrict__ deg,
                                              const float* __restrict__ W,
                                              unsigned* __restrict__ Wb_u32) {
    int g = blockIdx.x * 256 + threadIdx.x;
    if (g < N_NODES) deg[g] = 0;
    if (g < 512 * 48) {
        int row = g / 48, pair = g % 48;
        float lo = W[(size_t)row * OUT_FEATS + pair * 2];
        float hi = W[(size_t)row * OUT_FEATS + pair * 2 + 1];
        Wb_u32[g] = pack2bf(lo, hi);
    }
}

// ---------------------------------------------------------------------------
// k_hist: degree histogram + per-edge rank
// ---------------------------------------------------------------------------
__global__ __launch_bounds__(256) void k_hist(const int* __restrict__ dst,
                                              int* __restrict__ deg,
                                              int* __restrict__ rank) {
    int e = blockIdx.x * 256 + threadIdx.x;
    if (e < N_EDGES) rank[e] = atomicAdd(&deg[dst[e]], 1);
}

__global__ __launch_bounds__(256) void k_scan1(const int* __restrict__ in, int n,
                                               int* __restrict__ out, int* __restrict__ bsum) {
    int g = blockIdx.x * 256 + threadIdx.x;
    int lane = threadIdx.x & 63, wave = threadIdx.x >> 6;
    int v = (g < n) ? in[g] : 0;
    int orig = v;
    for (int off = 1; off < 64; off <<= 1) {
        int u = __shfl_up(v, off);
        if (lane >= off) v += u;
    }
    __shared__ int wsum[4];
    if (lane == 63) wsum[wave] = v;
    __syncthreads();
    if (threadIdx.x == 0) {
        int s = 0;
        for (int w = 0; w < 4; ++w) { int t = wsum[w]; wsum[w] = s; s += t; }
        bsum[blockIdx.x] = s;
    }
    __syncthreads();
    int excl = v - orig + wsum[wave];
    if (g < n) out[g] = excl;
}

__global__ __launch_bounds__(256) void k_scan3(int* __restrict__ pos, const int* __restrict__ bscan, int n) {
    int g = blockIdx.x * 256 + threadIdx.x;
    if (g < n) pos[g] += bscan[blockIdx.x];
}

// k_bin: atomic-free scatter using precomputed rank
__global__ __launch_bounds__(256) void k_bin(const int* __restrict__ dst, const int* __restrict__ src,
                                             const int* __restrict__ etypes,
                                             const int* __restrict__ pos, const int* __restrict__ rank,
                                             int* __restrict__ packed) {
    int e = blockIdx.x * 256 + threadIdx.x;
    if (e < N_EDGES) {
        int slot = pos[dst[e]] + rank[e];
        packed[slot] = src[e] | (etypes[e] << 16);  // src < 65536, et < 4
    }
}

// ---------------------------------------------------------------------------
// Per-node aggregation: 1 wave per node, float4 lanes, 2 edges per
// wave-instruction (lanes 0-23 edge A, lanes 32-55 edge B), 4-deep unroll
// -> 8 edges in flight. Half-waves merge via shfl_xor(32) at the end.
// ---------------------------------------------------------------------------
__global__ __launch_bounds__(64) void k_agg(const float4* __restrict__ feat4,
                                            const int* __restrict__ pos, const int* __restrict__ deg,
                                            const int* __restrict__ packed,
                                            unsigned* __restrict__ Scat_u32,
                                            float* __restrict__ counts) {
    const int d = blockIdx.x;
    const int lane = threadIdx.x;
    const int h = lane >> 5;        // half-wave: 0 -> even edges, 1 -> odd edges
    const int q = lane & 31;        // float4 index within the row (0..23 active)
    const bool act = q < 24;
    const int start = pos[d], cnt = deg[d];

    float4 a0 = {0,0,0,0}, a1 = {0,0,0,0}, a2 = {0,0,0,0}, a3 = {0,0,0,0};
    int c0 = 0, c1 = 0, c2 = 0, c3 = 0;
    const float4 zero = {0,0,0,0};

#define ACC(e, v)                                                              \
    if ((e) == 0)      { a0.x += (v).x; a0.y += (v).y; a0.z += (v).z; a0.w += (v).w; ++c0; } \
    else if ((e) == 1) { a1.x += (v).x; a1.y += (v).y; a1.z += (v).z; a1.w += (v).w; ++c1; } \
    else if ((e) == 2) { a2.x += (v).x; a2.y += (v).y; a2.z += (v).z; a2.w += (v).w; ++c2; } \
    else               { a3.x += (v).x; a3.y += (v).y; a3.z += (v).z; a3.w += (v).w; ++c3; }

    int i = 0;
    for (; i + 8 <= cnt; i += 8) {
        int p0 = packed[start + i + 0 + h];
        int p1 = packed[start + i + 2 + h];
        int p2 = packed[start + i + 4 + h];
        int p3 = packed[start + i + 6 + h];
        float4 v0 = act ? feat4[(size_t)(p0 & 0xFFFF) * 24 + q] : zero;
        float4 v1 = act ? feat4[(size_t)(p1 & 0xFFFF) * 24 + q] : zero;
        float4 v2 = act ? feat4[(size_t)(p2 & 0xFFFF) * 24 + q] : zero;
        float4 v3 = act ? feat4[(size_t)(p3 & 0xFFFF) * 24 + q] : zero;
        int e0 = p0 >> 16, e1 = p1 >> 16, e2 = p2 >> 16, e3 = p3 >> 16;
        ACC(e0, v0);
        ACC(e1, v1);
        ACC(e2, v2);
        ACC(e3, v3);
    }
    for (; i + 2 <= cnt; i += 2) {
        int p = packed[start + i + h];
        float4 v = act ? feat4[(size_t)(p & 0xFFFF) * 24 + q] : zero;
        int e = p >> 16;
        ACC(e, v);
    }
    if (i < cnt) {  // lone last edge -> half 0 only
        int p = packed[start + i];
        if (h == 0) {
            float4 v = act ? feat4[(size_t)(p & 0xFFFF) * 24 + q] : zero;
            int e = p >> 16;
            ACC(e, v);
        }
    }
#undef ACC

    // merge half-waves (lane ^ 32)
#define COMB(a) { a.x += __shfl_xor(a.x, 32); a.y += __shfl_xor(a.y, 32); \
                  a.z += __shfl_xor(a.z, 32); a.w += __shfl_xor(a.w, 32); }
    COMB(a0); COMB(a1); COMB(a2); COMB(a3);
#undef COMB
    c0 += __shfl_xor(c0, 32);
    c1 += __shfl_xor(c1, 32);
    c2 += __shfl_xor(c2, 32);
    c3 += __shfl_xor(c3, 32);

    if (h == 0 && act) {
        size_t base = (size_t)d * (KCAT / 2) + q * 2;  // u32 index; row stride 192
        uint2 s0 = { pack2bf(a0.x, a0.y), pack2bf(a0.z, a0.w) };
        uint2 s1 = { pack2bf(a1.x, a1.y), pack2bf(a1.z, a1.w) };
        uint2 s2 = { pack2bf(a2.x, a2.y), pack2bf(a2.z, a2.w) };
        uint2 s3 = { pack2bf(a3.x, a3.y), pack2bf(a3.z, a3.w) };
        *reinterpret_cast<uint2*>(&Scat_u32[base])       = s0;
        *reinterpret_cast<uint2*>(&Scat_u32[base + 48])  = s1;
        *reinterpret_cast<uint2*>(&Scat_u32[base + 96])  = s2;
        *reinterpret_cast<uint2*>(&Scat_u32[base + 144]) = s3;
    }
    if (lane < 4) counts[d * 4 + lane] = (float)(lane == 0 ? c0 : lane == 1 ? c1 : lane == 2 ? c2 : c3);
}

// ---------------------------------------------------------------------------
// MFMA GEMM: out[m][n] = sum_{k'<384} Scat[m][k'] * Wb[n][k'] + bias
// Block 128x128, 4 waves (2x2), K-step 96 (== one etype per step).
// ---------------------------------------------------------------------------
#define LDT 104  // padded LDS row (bf16 elems)

__global__ __launch_bounds__(256) void k_gemm(const __hip_bfloat16* __restrict__ Scat,
                                              const short* __restrict__ Wb,
                                              const float* __restrict__ b,
                                              const float* __restrict__ counts,
                                              float* __restrict__ out) {
    __shared__ __align__(16) __hip_bfloat16 As[128][LDT];
    __shared__ __align__(16) __hip_bfloat16 Bs[128][LDT];
    const int m0 = blockIdx.x * 128;
    const int tid = threadIdx.x, lane = tid & 63, wave = tid >> 6;
    const int wm = wave >> 1, wn = wave & 1;

    f32x4 acc[4][4];
#pragma unroll
    for (int i = 0; i < 4; ++i)
#pragma unroll
        for (int jj = 0; jj < 4; ++jj) acc[i][jj] = (f32x4){0.f, 0.f, 0.f, 0.f};

    for (int ks = 0; ks < 4; ++ks) {  // ks == etype
#pragma unroll
        for (int it = 0; it < 6; ++it) {
            int idx = tid + it * 256;          // 0..1535
            int row = idx / 12, c8 = idx % 12;
            int gm = m0 + row;
            if (gm > N_NODES - 1) gm = N_NODES - 1;
            short8 v = *reinterpret_cast<const short8*>(&Scat[(size_t)gm * KCAT + ks * IN_FEATS + c8 * 8]);
            *reinterpret_cast<short8*>(&As[row][c8 * 8]) = v;
        }
#pragma unroll
        for (int it = 0; it < 6; ++it) {
            int idx = tid + it * 256;          // 0..1535
            int row = idx / 12, c8 = idx % 12;
            short8 v = *reinterpret_cast<const short8*>(&Wb[((size_t)ks * OUT_FEATS + row) * IN_FEATS + c8 * 8]);
            *reinterpret_cast<short8*>(&Bs[row][c8 * 8]) = v;
        }
        __syncthreads();
#pragma unroll
        for (int kk = 0; kk < 3; ++kk) {
            short8 af[4], bf[4];
#pragma unroll
            for (int mi = 0; mi < 4; ++mi)
                af[mi] = *reinterpret_cast<const short8*>(&As[wm * 64 + mi * 16 + (lane & 15)][kk * 32 + (lane >> 4) * 8]);
#pragma unroll
            for (int ni = 0; ni < 4; ++ni)
                bf[ni] = *reinterpret_cast<const short8*>(&Bs[wn * 64 + ni * 16 + (lane & 15)][kk * 32 + (lane >> 4) * 8]);
#pragma unroll
            for (int mi = 0; mi < 4; ++mi)
#pragma unroll
                for (int ni = 0; ni < 4; ++ni)
                    acc[mi][ni] = __builtin_amdgcn_mfma_f32_16x16x32_bf16(af[mi], bf[ni], acc[mi][ni], 0, 0, 0);
        }
        __syncthreads();
    }

#pragma unroll
    for (int mi = 0; mi < 4; ++mi) {
#pragma unroll
        for (int r = 0; r < 4; ++r) {
            int m = m0 + wm * 64 + mi * 16 + (lane >> 4) * 4 + r;
            if (m < N_NODES) {
                float4 c4 = *reinterpret_cast<const float4*>(&counts[m * 4]);
#pragma unroll
                for (int ni = 0; ni < 4; ++ni) {
                    int n = wn * 64 + ni * 16 + (lane & 15);
                    float bias = c4.x * b[n] + c4.y * b[OUT_FEATS + n] +
                                 c4.z * b[2 * OUT_FEATS + n] + c4.w * b[3 * OUT_FEATS + n];
                    out[(size_t)m * OUT_FEATS + n] = acc[mi][ni][r] + bias;
                }
            }
        }
    }
}

// ---------------------------------------------------------------------------
// Fallback (ws too small): direct per-(edge, j) dot product with atomics.
// ---------------------------------------------------------------------------
__global__ __launch_bounds__(256) void edge_direct(const float* __restrict__ feat,
                                                   const int* __restrict__ etypes,
                                                   const int* __restrict__ src,
                                                   const int* __restrict__ dst,
                                                   const float* __restrict__ W,
                                                   const float* __restrict__ b,
                                                   float* __restrict__ out) {
    int gid = blockIdx.x * 256 + threadIdx.x;
    int e = gid >> 7;
    int j = gid & 127;
    if (e >= N_EDGES) return;
    int et = etypes[e];
    int s = src[e];
    int d = dst[e];
    const float* f = feat + (size_t)s * IN_FEATS;
    const float* w = W + ((size_t)et * OUT_FEATS + j) * OUT_FEATS;
    float acc = b[et * OUT_FEATS + j];
    for (int k = 0; k < IN_FEATS; ++k) acc += f[k] * w[k];
    atomicAdd(&out[(size_t)d * OUT_FEATS + j], acc);
}

extern "C" void kernel_launch(void* const* d_in, const int* in_sizes, int n_in,
                              void* d_out, int out_size, void* d_ws, size_t ws_size,
                              hipStream_t stream) {
    const float* feat  = (const float*)d_in[0];
    const int*   etyps = (const int*)d_in[1];
    const int*   src   = (const int*)d_in[2];
    const int*   dst   = (const int*)d_in[3];
    const float* W     = (const float*)d_in[4];
    const float* b     = (const float*)d_in[5];
    float* out = (float*)d_out;

    const size_t off_scat   = 0;                                        // 38,400,000
    const size_t off_counts = off_scat + (size_t)N_NODES * KCAT * 2;    // +800,000
    const size_t off_deg    = off_counts + (size_t)N_NODES * 4 * 4;     // +200,000
    const size_t off_pos    = off_deg + (size_t)N_NODES * 4;            // +200,000
    const size_t off_rank   = off_pos + (size_t)N_NODES * 4;            // +2,000,000
    const size_t off_packed = off_rank + (size_t)N_EDGES * 4;           // +2,000,000
    const size_t off_bsum   = off_packed + (size_t)N_EDGES * 4;
    const size_t off_bscan  = off_bsum + 1024;
    const size_t off_scrap  = off_bscan + 1024;
    const size_t off_wb     = off_scrap + 1024;                         // +98,304
    const size_t need = off_wb + (size_t)512 * IN_FEATS * 2;

    if (ws_size >= need) {
        char* ws = (char*)d_ws;
        __hip_bfloat16* Scat = (__hip_bfloat16*)(ws + off_scat);
        unsigned* Scat_u32 = (unsigned*)(ws + off_scat);
        float* counts = (float*)(ws + off_counts);
        int* deg    = (int*)(ws + off_deg);
        int* pos    = (int*)(ws + off_pos);
        int* rank   = (int*)(ws + off_rank);
        int* packed = (int*)(ws + off_packed);
        int* bsum   = (int*)(ws + off_bsum);
        int* bscan  = (int*)(ws + off_bscan);
        int* scrap  = (int*)(ws + off_scrap);
        unsigned* Wb_u32 = (unsigned*)(ws + off_wb);
        short* Wb = (short*)(ws + off_wb);

        const int nScanBlocks = (N_NODES + 255) / 256;  // 196
        const int nEdgeBlocks = (N_EDGES + 255) / 256;  // 1954

        k_init<<<nScanBlocks, 256, 0, stream>>>(deg, W, Wb_u32);
        k_hist<<<nEdgeBlocks, 256, 0, stream>>>(dst, deg, rank);
        k_scan1<<<nScanBlocks, 256, 0, stream>>>(deg, N_NODES, pos, bsum);
        k_scan1<<<1, 256, 0, stream>>>(bsum, nScanBlocks, bscan, scrap);
        k_scan3<<<nScanBlocks, 256, 0, stream>>>(pos, bscan, N_NODES);
        k_bin<<<nEdgeBlocks, 256, 0, stream>>>(dst, src, etyps, pos, rank, packed);
        k_agg<<<N_NODES, 64, 0, stream>>>((const float4*)feat, pos, deg, packed, Scat_u32, counts);
        k_gemm<<<(N_NODES + 127) / 128, 256, 0, stream>>>(Scat, Wb, b, counts, out);
    } else {
        hipMemsetAsync(d_out, 0, (size_t)out_size * sizeof(float), stream);
        int nthreads = N_EDGES * OUT_FEATS;
        edge_direct<<<nthreads / 256, 256, 0, stream>>>(feat, etyps, src, dst, W, b, out);
    }
}

// Round 8
// 110.385 us; speedup vs baseline: 1.0517x; 1.0517x over previous
//
#include <hip/hip_runtime.h>
#include <hip/hip_bf16.h>

#define N_NODES 50000
#define N_EDGES 500000
#define IN_FEATS 96
#define OUT_FEATS 128
#define N_ETYPES 4
#define KCAT (N_ETYPES * IN_FEATS)  // 384

typedef __attribute__((ext_vector_type(8))) short short8;
typedef __attribute__((ext_vector_type(4))) float f32x4;

static __device__ inline short f2bf_bits(float f) {
    __hip_bfloat16 h = __float2bfloat16(f);
    return *reinterpret_cast<short*>(&h);
}
static __device__ inline unsigned pack2bf(float lo, float hi) {
    unsigned l = (unsigned short)f2bf_bits(lo);
    unsigned h = (unsigned short)f2bf_bits(hi);
    return l | (h << 16);
}

// ---------------------------------------------------------------------------
// k_init: zero deg[] AND pre-convert W (f32 [4][128][128], first 96 cols) to
// bf16 Wb [4*128][96] (stored as u32 pairs).
// ---------------------------------------------------------------------------
__global__ __launch_bounds__(256) void k_init(int* __restrict__ deg,
                                              const float* __restrict__ W,
                                              unsigned* __restrict__ Wb_u32) {
    int g = blockIdx.x * 256 + threadIdx.x;
    if (g < N_NODES) deg[g] = 0;
    if (g < 512 * 48) {
        int row = g / 48, pair = g % 48;
        float lo = W[(size_t)row * OUT_FEATS + pair * 2];
        float hi = W[(size_t)row * OUT_FEATS + pair * 2 + 1];
        Wb_u32[g] = pack2bf(lo, hi);
    }
}

// ---------------------------------------------------------------------------
// k_hist: degree histogram + per-edge rank
// ---------------------------------------------------------------------------
__global__ __launch_bounds__(256) void k_hist(const int* __restrict__ dst,
                                              int* __restrict__ deg,
                                              int* __restrict__ rank) {
    int e = blockIdx.x * 256 + threadIdx.x;
    if (e < N_EDGES) rank[e] = atomicAdd(&deg[dst[e]], 1);
}

__global__ __launch_bounds__(256) void k_scan1(const int* __restrict__ in, int n,
                                               int* __restrict__ out, int* __restrict__ bsum) {
    int g = blockIdx.x * 256 + threadIdx.x;
    int lane = threadIdx.x & 63, wave = threadIdx.x >> 6;
    int v = (g < n) ? in[g] : 0;
    int orig = v;
    for (int off = 1; off < 64; off <<= 1) {
        int u = __shfl_up(v, off);
        if (lane >= off) v += u;
    }
    __shared__ int wsum[4];
    if (lane == 63) wsum[wave] = v;
    __syncthreads();
    if (threadIdx.x == 0) {
        int s = 0;
        for (int w = 0; w < 4; ++w) { int t = wsum[w]; wsum[w] = s; s += t; }
        bsum[blockIdx.x] = s;
    }
    __syncthreads();
    int excl = v - orig + wsum[wave];
    if (g < n) out[g] = excl;
}

__global__ __launch_bounds__(256) void k_scan3(int* __restrict__ pos, const int* __restrict__ bscan, int n) {
    int g = blockIdx.x * 256 + threadIdx.x;
    if (g < n) pos[g] += bscan[blockIdx.x];
}

// k_bin: atomic-free scatter using precomputed rank
__global__ __launch_bounds__(256) void k_bin(const int* __restrict__ dst, const int* __restrict__ src,
                                             const int* __restrict__ etypes,
                                             const int* __restrict__ pos, const int* __restrict__ rank,
                                             int* __restrict__ packed) {
    int e = blockIdx.x * 256 + threadIdx.x;
    if (e < N_EDGES) {
        int slot = pos[dst[e]] + rank[e];
        packed[slot] = src[e] | (etypes[e] << 16);  // src < 65536, et < 4
    }
}

// ---------------------------------------------------------------------------
// Per-node aggregation: 1 wave per TWO nodes, interleaved 4-deep per node
// -> up to 8 independent gathers in flight per group, wave-uniform
// predication per edge (deg is wave-uniform). float2 lanes (48 active).
// ---------------------------------------------------------------------------
__global__ __launch_bounds__(64) void k_agg(const float2* __restrict__ feat2,
                                            const int* __restrict__ pos, const int* __restrict__ deg,
                                            const int* __restrict__ packed,
                                            unsigned* __restrict__ Scat_u32,
                                            float* __restrict__ counts) {
    const int d0 = blockIdx.x * 2;
    const int d1 = d0 + 1;  // N_NODES even
    const int lane = threadIdx.x;
    const bool act = lane < 48;
    const int start0 = pos[d0], cnt0 = deg[d0];
    const int start1 = pos[d1], cnt1 = deg[d1];

    float2 A0 = {0,0}, A1 = {0,0}, A2 = {0,0}, A3 = {0,0};  // node d0 per-etype
    float2 B0 = {0,0}, B1 = {0,0}, B2 = {0,0}, B3 = {0,0};  // node d1 per-etype
    int ca0 = 0, ca1 = 0, ca2 = 0, ca3 = 0;
    int cb0 = 0, cb1 = 0, cb2 = 0, cb3 = 0;
    const float2 zero = {0,0};

#define ACCA(e, v)                                                \
    if ((e) == 0)      { A0.x += (v).x; A0.y += (v).y; ++ca0; }   \
    else if ((e) == 1) { A1.x += (v).x; A1.y += (v).y; ++ca1; }   \
    else if ((e) == 2) { A2.x += (v).x; A2.y += (v).y; ++ca2; }   \
    else               { A3.x += (v).x; A3.y += (v).y; ++ca3; }
#define ACCB(e, v)                                                \
    if ((e) == 0)      { B0.x += (v).x; B0.y += (v).y; ++cb0; }   \
    else if ((e) == 1) { B1.x += (v).x; B1.y += (v).y; ++cb1; }   \
    else if ((e) == 2) { B2.x += (v).x; B2.y += (v).y; ++cb2; }   \
    else               { B3.x += (v).x; B3.y += (v).y; ++cb3; }

    const int mx = cnt0 > cnt1 ? cnt0 : cnt1;
    for (int i = 0; i < mx; i += 4) {
        // wave-uniform validity per edge slot
        const bool k0 = i + 0 < cnt0, k1 = i + 1 < cnt0, k2 = i + 2 < cnt0, k3 = i + 3 < cnt0;
        const bool m0 = i + 0 < cnt1, m1 = i + 1 < cnt1, m2 = i + 2 < cnt1, m3 = i + 3 < cnt1;
        // stage 1: packed loads (independent)
        int p0 = 0, p1 = 0, p2 = 0, p3 = 0, q0 = 0, q1 = 0, q2 = 0, q3 = 0;
        if (k0) p0 = packed[start0 + i + 0];
        if (k1) p1 = packed[start0 + i + 1];
        if (k2) p2 = packed[start0 + i + 2];
        if (k3) p3 = packed[start0 + i + 3];
        if (m0) q0 = packed[start1 + i + 0];
        if (m1) q1 = packed[start1 + i + 1];
        if (m2) q2 = packed[start1 + i + 2];
        if (m3) q3 = packed[start1 + i + 3];
        // stage 2: up to 8 independent row gathers in flight
        float2 v0 = (k0 && act) ? feat2[(size_t)(p0 & 0xFFFF) * 48 + lane] : zero;
        float2 v1 = (k1 && act) ? feat2[(size_t)(p1 & 0xFFFF) * 48 + lane] : zero;
        float2 v2 = (k2 && act) ? feat2[(size_t)(p2 & 0xFFFF) * 48 + lane] : zero;
        float2 v3 = (k3 && act) ? feat2[(size_t)(p3 & 0xFFFF) * 48 + lane] : zero;
        float2 w0 = (m0 && act) ? feat2[(size_t)(q0 & 0xFFFF) * 48 + lane] : zero;
        float2 w1 = (m1 && act) ? feat2[(size_t)(q1 & 0xFFFF) * 48 + lane] : zero;
        float2 w2 = (m2 && act) ? feat2[(size_t)(q2 & 0xFFFF) * 48 + lane] : zero;
        float2 w3 = (m3 && act) ? feat2[(size_t)(q3 & 0xFFFF) * 48 + lane] : zero;
        // stage 3: accumulate (wave-uniform etype branches)
        if (k0) { int e = p0 >> 16; ACCA(e, v0); }
        if (k1) { int e = p1 >> 16; ACCA(e, v1); }
        if (k2) { int e = p2 >> 16; ACCA(e, v2); }
        if (k3) { int e = p3 >> 16; ACCA(e, v3); }
        if (m0) { int e = q0 >> 16; ACCB(e, w0); }
        if (m1) { int e = q1 >> 16; ACCB(e, w1); }
        if (m2) { int e = q2 >> 16; ACCB(e, w2); }
        if (m3) { int e = q3 >> 16; ACCB(e, w3); }
    }
#undef ACCA
#undef ACCB

    if (act) {
        size_t base0 = (size_t)d0 * (KCAT / 2) + lane;  // u32 row stride 192
        Scat_u32[base0]       = pack2bf(A0.x, A0.y);
        Scat_u32[base0 + 48]  = pack2bf(A1.x, A1.y);
        Scat_u32[base0 + 96]  = pack2bf(A2.x, A2.y);
        Scat_u32[base0 + 144] = pack2bf(A3.x, A3.y);
        size_t base1 = (size_t)d1 * (KCAT / 2) + lane;
        Scat_u32[base1]       = pack2bf(B0.x, B0.y);
        Scat_u32[base1 + 48]  = pack2bf(B1.x, B1.y);
        Scat_u32[base1 + 96]  = pack2bf(B2.x, B2.y);
        Scat_u32[base1 + 144] = pack2bf(B3.x, B3.y);
    }
    if (lane < 4) {
        counts[d0 * 4 + lane] = (float)(lane == 0 ? ca0 : lane == 1 ? ca1 : lane == 2 ? ca2 : ca3);
    } else if (lane < 8) {
        int l = lane - 4;
        counts[d1 * 4 + l] = (float)(l == 0 ? cb0 : l == 1 ? cb1 : l == 2 ? cb2 : cb3);
    }
}

// ---------------------------------------------------------------------------
// MFMA GEMM: out[m][n] = sum_{k'<384} Scat[m][k'] * Wb[n][k'] + bias
// Block 128x128, 4 waves (2x2), K-step 96 (== one etype per step).
// ---------------------------------------------------------------------------
#define LDT 104  // padded LDS row (bf16 elems)

__global__ __launch_bounds__(256) void k_gemm(const __hip_bfloat16* __restrict__ Scat,
                                              const short* __restrict__ Wb,
                                              const float* __restrict__ b,
                                              const float* __restrict__ counts,
                                              float* __restrict__ out) {
    __shared__ __align__(16) __hip_bfloat16 As[128][LDT];
    __shared__ __align__(16) __hip_bfloat16 Bs[128][LDT];
    const int m0 = blockIdx.x * 128;
    const int tid = threadIdx.x, lane = tid & 63, wave = tid >> 6;
    const int wm = wave >> 1, wn = wave & 1;

    f32x4 acc[4][4];
#pragma unroll
    for (int i = 0; i < 4; ++i)
#pragma unroll
        for (int jj = 0; jj < 4; ++jj) acc[i][jj] = (f32x4){0.f, 0.f, 0.f, 0.f};

    for (int ks = 0; ks < 4; ++ks) {  // ks == etype
#pragma unroll
        for (int it = 0; it < 6; ++it) {
            int idx = tid + it * 256;          // 0..1535
            int row = idx / 12, c8 = idx % 12;
            int gm = m0 + row;
            if (gm > N_NODES - 1) gm = N_NODES - 1;
            short8 v = *reinterpret_cast<const short8*>(&Scat[(size_t)gm * KCAT + ks * IN_FEATS + c8 * 8]);
            *reinterpret_cast<short8*>(&As[row][c8 * 8]) = v;
        }
#pragma unroll
        for (int it = 0; it < 6; ++it) {
            int idx = tid + it * 256;          // 0..1535
            int row = idx / 12, c8 = idx % 12;
            short8 v = *reinterpret_cast<const short8*>(&Wb[((size_t)ks * OUT_FEATS + row) * IN_FEATS + c8 * 8]);
            *reinterpret_cast<short8*>(&Bs[row][c8 * 8]) = v;
        }
        __syncthreads();
#pragma unroll
        for (int kk = 0; kk < 3; ++kk) {
            short8 af[4], bf[4];
#pragma unroll
            for (int mi = 0; mi < 4; ++mi)
                af[mi] = *reinterpret_cast<const short8*>(&As[wm * 64 + mi * 16 + (lane & 15)][kk * 32 + (lane >> 4) * 8]);
#pragma unroll
            for (int ni = 0; ni < 4; ++ni)
                bf[ni] = *reinterpret_cast<const short8*>(&Bs[wn * 64 + ni * 16 + (lane & 15)][kk * 32 + (lane >> 4) * 8]);
#pragma unroll
            for (int mi = 0; mi < 4; ++mi)
#pragma unroll
                for (int ni = 0; ni < 4; ++ni)
                    acc[mi][ni] = __builtin_amdgcn_mfma_f32_16x16x32_bf16(af[mi], bf[ni], acc[mi][ni], 0, 0, 0);
        }
        __syncthreads();
    }

#pragma unroll
    for (int mi = 0; mi < 4; ++mi) {
#pragma unroll
        for (int r = 0; r < 4; ++r) {
            int m = m0 + wm * 64 + mi * 16 + (lane >> 4) * 4 + r;
            if (m < N_NODES) {
                float4 c4 = *reinterpret_cast<const float4*>(&counts[m * 4]);
#pragma unroll
                for (int ni = 0; ni < 4; ++ni) {
                    int n = wn * 64 + ni * 16 + (lane & 15);
                    float bias = c4.x * b[n] + c4.y * b[OUT_FEATS + n] +
                                 c4.z * b[2 * OUT_FEATS + n] + c4.w * b[3 * OUT_FEATS + n];
                    out[(size_t)m * OUT_FEATS + n] = acc[mi][ni][r] + bias;
                }
            }
        }
    }
}

// ---------------------------------------------------------------------------
// Fallback (ws too small): direct per-(edge, j) dot product with atomics.
// ---------------------------------------------------------------------------
__global__ __launch_bounds__(256) void edge_direct(const float* __restrict__ feat,
                                                   const int* __restrict__ etypes,
                                                   const int* __restrict__ src,
                                                   const int* __restrict__ dst,
                                                   const float* __restrict__ W,
                                                   const float* __restrict__ b,
                                                   float* __restrict__ out) {
    int gid = blockIdx.x * 256 + threadIdx.x;
    int e = gid >> 7;
    int j = gid & 127;
    if (e >= N_EDGES) return;
    int et = etypes[e];
    int s = src[e];
    int d = dst[e];
    const float* f = feat + (size_t)s * IN_FEATS;
    const float* w = W + ((size_t)et * OUT_FEATS + j) * OUT_FEATS;
    float acc = b[et * OUT_FEATS + j];
    for (int k = 0; k < IN_FEATS; ++k) acc += f[k] * w[k];
    atomicAdd(&out[(size_t)d * OUT_FEATS + j], acc);
}

extern "C" void kernel_launch(void* const* d_in, const int* in_sizes, int n_in,
                              void* d_out, int out_size, void* d_ws, size_t ws_size,
                              hipStream_t stream) {
    const float* feat  = (const float*)d_in[0];
    const int*   etyps = (const int*)d_in[1];
    const int*   src   = (const int*)d_in[2];
    const int*   dst   = (const int*)d_in[3];
    const float* W     = (const float*)d_in[4];
    const float* b     = (const float*)d_in[5];
    float* out = (float*)d_out;

    const size_t off_scat   = 0;                                        // 38,400,000
    const size_t off_counts = off_scat + (size_t)N_NODES * KCAT * 2;    // +800,000
    const size_t off_deg    = off_counts + (size_t)N_NODES * 4 * 4;     // +200,000
    const size_t off_pos    = off_deg + (size_t)N_NODES * 4;            // +200,000
    const size_t off_rank   = off_pos + (size_t)N_NODES * 4;            // +2,000,000
    const size_t off_packed = off_rank + (size_t)N_EDGES * 4;           // +2,000,000
    const size_t off_bsum   = off_packed + (size_t)N_EDGES * 4;
    const size_t off_bscan  = off_bsum + 1024;
    const size_t off_scrap  = off_bscan + 1024;
    const size_t off_wb     = off_scrap + 1024;                         // +98,304
    const size_t need = off_wb + (size_t)512 * IN_FEATS * 2;

    if (ws_size >= need) {
        char* ws = (char*)d_ws;
        __hip_bfloat16* Scat = (__hip_bfloat16*)(ws + off_scat);
        unsigned* Scat_u32 = (unsigned*)(ws + off_scat);
        float* counts = (float*)(ws + off_counts);
        int* deg    = (int*)(ws + off_deg);
        int* pos    = (int*)(ws + off_pos);
        int* rank   = (int*)(ws + off_rank);
        int* packed = (int*)(ws + off_packed);
        int* bsum   = (int*)(ws + off_bsum);
        int* bscan  = (int*)(ws + off_bscan);
        int* scrap  = (int*)(ws + off_scrap);
        unsigned* Wb_u32 = (unsigned*)(ws + off_wb);
        short* Wb = (short*)(ws + off_wb);

        const int nScanBlocks = (N_NODES + 255) / 256;  // 196
        const int nEdgeBlocks = (N_EDGES + 255) / 256;  // 1954

        k_init<<<nScanBlocks, 256, 0, stream>>>(deg, W, Wb_u32);
        k_hist<<<nEdgeBlocks, 256, 0, stream>>>(dst, deg, rank);
        k_scan1<<<nScanBlocks, 256, 0, stream>>>(deg, N_NODES, pos, bsum);
        k_scan1<<<1, 256, 0, stream>>>(bsum, nScanBlocks, bscan, scrap);
        k_scan3<<<nScanBlocks, 256, 0, stream>>>(pos, bscan, N_NODES);
        k_bin<<<nEdgeBlocks, 256, 0, stream>>>(dst, src, etyps, pos, rank, packed);
        k_agg<<<N_NODES / 2, 64, 0, stream>>>((const float2*)feat, pos, deg, packed, Scat_u32, counts);
        k_gemm<<<(N_NODES + 127) / 128, 256, 0, stream>>>(Scat, Wb, b, counts, out);
    } else {
        hipMemsetAsync(d_out, 0, (size_t)out_size * sizeof(float), stream);
        int nthreads = N_EDGES * OUT_FEATS;
        edge_direct<<<nthreads / 256, 256, 0, stream>>>(feat, etyps, src, dst, W, b, out);
    }
}

// Round 9
// 107.587 us; speedup vs baseline: 1.0791x; 1.0260x over previous
//
#include <hip/hip_runtime.h>
#include <hip/hip_bf16.h>

#define N_NODES 50000
#define N_EDGES 500000
#define IN_FEATS 96
#define OUT_FEATS 128
#define N_ETYPES 4
#define KCAT (N_ETYPES * IN_FEATS)  // 384

typedef __attribute__((ext_vector_type(8))) short short8;
typedef __attribute__((ext_vector_type(4))) float f32x4;

static __device__ inline short f2bf_bits(float f) {
    __hip_bfloat16 h = __float2bfloat16(f);
    return *reinterpret_cast<short*>(&h);
}
static __device__ inline unsigned pack2bf(float lo, float hi) {
    unsigned l = (unsigned short)f2bf_bits(lo);
    unsigned h = (unsigned short)f2bf_bits(hi);
    return l | (h << 16);
}

// ---------------------------------------------------------------------------
// k_init: zero deg[] AND pre-convert W (f32 [4][128][128], first 96 cols) to
// bf16 Wb [4*128][96] (stored as u32 pairs).
// ---------------------------------------------------------------------------
__global__ __launch_bounds__(256) void k_init(int* __restrict__ deg,
                                              const float* __restrict__ W,
                                              unsigned* __restrict__ Wb_u32) {
    int g = blockIdx.x * 256 + threadIdx.x;
    if (g < N_NODES) deg[g] = 0;
    if (g < 512 * 48) {
        int row = g / 48, pair = g % 48;
        float lo = W[(size_t)row * OUT_FEATS + pair * 2];
        float hi = W[(size_t)row * OUT_FEATS + pair * 2 + 1];
        Wb_u32[g] = pack2bf(lo, hi);
    }
}

// ---------------------------------------------------------------------------
// k_hist: degree histogram + per-edge rank
// ---------------------------------------------------------------------------
__global__ __launch_bounds__(256) void k_hist(const int* __restrict__ dst,
                                              int* __restrict__ deg,
                                              int* __restrict__ rank) {
    int e = blockIdx.x * 256 + threadIdx.x;
    if (e < N_EDGES) rank[e] = atomicAdd(&deg[dst[e]], 1);
}

__global__ __launch_bounds__(256) void k_scan1(const int* __restrict__ in, int n,
                                               int* __restrict__ out, int* __restrict__ bsum) {
    int g = blockIdx.x * 256 + threadIdx.x;
    int lane = threadIdx.x & 63, wave = threadIdx.x >> 6;
    int v = (g < n) ? in[g] : 0;
    int orig = v;
    for (int off = 1; off < 64; off <<= 1) {
        int u = __shfl_up(v, off);
        if (lane >= off) v += u;
    }
    __shared__ int wsum[4];
    if (lane == 63) wsum[wave] = v;
    __syncthreads();
    if (threadIdx.x == 0) {
        int s = 0;
        for (int w = 0; w < 4; ++w) { int t = wsum[w]; wsum[w] = s; s += t; }
        bsum[blockIdx.x] = s;
    }
    __syncthreads();
    int excl = v - orig + wsum[wave];
    if (g < n) out[g] = excl;
}

// k_scan3: each block computes its own prefix over bsum (196 ints) then adds.
// (folds the former middle scan kernel away)
__global__ __launch_bounds__(256) void k_scan3(int* __restrict__ pos, const int* __restrict__ bsum, int n) {
    const int b = blockIdx.x;
    const int t = threadIdx.x;
    const int lane = t & 63, wave = t >> 6;
    __shared__ int ws[4];
    int v = (t < b) ? bsum[t] : 0;   // b <= 195 < 256
#pragma unroll
    for (int off = 32; off > 0; off >>= 1) v += __shfl_down(v, off);
    if (lane == 0) ws[wave] = v;
    __syncthreads();
    if (t == 0) ws[0] = ws[0] + ws[1] + ws[2] + ws[3];
    __syncthreads();
    int prefix = ws[0];
    int g = b * 256 + t;
    if (g < n) pos[g] += prefix;
}

// k_bin: atomic-free scatter using precomputed rank
__global__ __launch_bounds__(256) void k_bin(const int* __restrict__ dst, const int* __restrict__ src,
                                             const int* __restrict__ etypes,
                                             const int* __restrict__ pos, const int* __restrict__ rank,
                                             int* __restrict__ packed) {
    int e = blockIdx.x * 256 + threadIdx.x;
    if (e < N_EDGES) {
        int slot = pos[dst[e]] + rank[e];
        packed[slot] = src[e] | (etypes[e] << 16);  // src < 65536, et < 4
    }
}

// ---------------------------------------------------------------------------
// Per-node aggregation (r5-proven form): 1 wave per node, float2 lanes,
// 4-deep unrolled gathers for ILP. Scat[d][et*96+k] bf16; counts f32.
// ---------------------------------------------------------------------------
__global__ __launch_bounds__(64) void k_agg(const float2* __restrict__ feat2,
                                            const int* __restrict__ pos, const int* __restrict__ deg,
                                            const int* __restrict__ packed,
                                            unsigned* __restrict__ Scat_u32,
                                            float* __restrict__ counts) {
    const int d = blockIdx.x;
    const int lane = threadIdx.x;
    const bool act = lane < 48;
    const int start = pos[d], cnt = deg[d];

    float2 a0 = {0.f, 0.f}, a1 = {0.f, 0.f}, a2 = {0.f, 0.f}, a3 = {0.f, 0.f};
    int c0 = 0, c1 = 0, c2 = 0, c3 = 0;
    const float2 zero = {0.f, 0.f};

    int i = 0;
    for (; i + 4 <= cnt; i += 4) {
        int p0 = packed[start + i + 0];
        int p1 = packed[start + i + 1];
        int p2 = packed[start + i + 2];
        int p3 = packed[start + i + 3];
        float2 v0 = act ? feat2[(size_t)(p0 & 0xFFFF) * 48 + lane] : zero;
        float2 v1 = act ? feat2[(size_t)(p1 & 0xFFFF) * 48 + lane] : zero;
        float2 v2 = act ? feat2[(size_t)(p2 & 0xFFFF) * 48 + lane] : zero;
        float2 v3 = act ? feat2[(size_t)(p3 & 0xFFFF) * 48 + lane] : zero;
        int e0 = p0 >> 16, e1 = p1 >> 16, e2 = p2 >> 16, e3 = p3 >> 16;
        if (e0 == 0) { a0.x += v0.x; a0.y += v0.y; ++c0; }
        else if (e0 == 1) { a1.x += v0.x; a1.y += v0.y; ++c1; }
        else if (e0 == 2) { a2.x += v0.x; a2.y += v0.y; ++c2; }
        else              { a3.x += v0.x; a3.y += v0.y; ++c3; }
        if (e1 == 0) { a0.x += v1.x; a0.y += v1.y; ++c0; }
        else if (e1 == 1) { a1.x += v1.x; a1.y += v1.y; ++c1; }
        else if (e1 == 2) { a2.x += v1.x; a2.y += v1.y; ++c2; }
        else              { a3.x += v1.x; a3.y += v1.y; ++c3; }
        if (e2 == 0) { a0.x += v2.x; a0.y += v2.y; ++c0; }
        else if (e2 == 1) { a1.x += v2.x; a1.y += v2.y; ++c1; }
        else if (e2 == 2) { a2.x += v2.x; a2.y += v2.y; ++c2; }
        else              { a3.x += v2.x; a3.y += v2.y; ++c3; }
        if (e3 == 0) { a0.x += v3.x; a0.y += v3.y; ++c0; }
        else if (e3 == 1) { a1.x += v3.x; a1.y += v3.y; ++c1; }
        else if (e3 == 2) { a2.x += v3.x; a2.y += v3.y; ++c2; }
        else              { a3.x += v3.x; a3.y += v3.y; ++c3; }
    }
    for (; i < cnt; ++i) {
        int p = packed[start + i];
        float2 v = act ? feat2[(size_t)(p & 0xFFFF) * 48 + lane] : zero;
        int e = p >> 16;
        if (e == 0) { a0.x += v.x; a0.y += v.y; ++c0; }
        else if (e == 1) { a1.x += v.x; a1.y += v.y; ++c1; }
        else if (e == 2) { a2.x += v.x; a2.y += v.y; ++c2; }
        else              { a3.x += v.x; a3.y += v.y; ++c3; }
    }

    if (act) {
        size_t base = (size_t)d * (KCAT / 2) + lane;  // u32 row stride 192
        Scat_u32[base]       = pack2bf(a0.x, a0.y);
        Scat_u32[base + 48]  = pack2bf(a1.x, a1.y);
        Scat_u32[base + 96]  = pack2bf(a2.x, a2.y);
        Scat_u32[base + 144] = pack2bf(a3.x, a3.y);
    }
    if (lane < 4) counts[d * 4 + lane] = (float)(lane == 0 ? c0 : lane == 1 ? c1 : lane == 2 ? c2 : c3);
}

// ---------------------------------------------------------------------------
// MFMA GEMM, LDS-free: A-frags gathered directly from Scat (block-local 96 KB,
// L2-hot), B-frags directly from Wb (96 KB global table, L2-resident).
// No barriers. Block 128x128, 4 waves (2x2). Same fragment mapping as the
// previous (verified) LDS version.
// ---------------------------------------------------------------------------
__global__ __launch_bounds__(256) void k_gemm(const __hip_bfloat16* __restrict__ Scat,
                                              const short* __restrict__ Wb,
                                              const float* __restrict__ b,
                                              const float* __restrict__ counts,
                                              float* __restrict__ out) {
    const int m0 = blockIdx.x * 128;
    const int tid = threadIdx.x, lane = tid & 63, wave = tid >> 6;
    const int wm = wave >> 1, wn = wave & 1;

    // per-mi A base pointers (row clamped for the tail block)
    const __hip_bfloat16* abase[4];
#pragma unroll
    for (int mi = 0; mi < 4; ++mi) {
        int row = m0 + wm * 64 + mi * 16 + (lane & 15);
        if (row > N_NODES - 1) row = N_NODES - 1;
        abase[mi] = Scat + (size_t)row * KCAT + (lane >> 4) * 8;
    }
    // per-ni B base pointers
    const short* bbase[4];
#pragma unroll
    for (int ni = 0; ni < 4; ++ni) {
        int brow = wn * 64 + ni * 16 + (lane & 15);
        bbase[ni] = Wb + (size_t)brow * IN_FEATS + (lane >> 4) * 8;
    }

    f32x4 acc[4][4];
#pragma unroll
    for (int i = 0; i < 4; ++i)
#pragma unroll
        for (int jj = 0; jj < 4; ++jj) acc[i][jj] = (f32x4){0.f, 0.f, 0.f, 0.f};

#pragma unroll
    for (int ks = 0; ks < 4; ++ks) {  // ks == etype
        // B fragments for this etype: 12 x short8, register-resident
        short8 bf[3][4];
#pragma unroll
        for (int kk = 0; kk < 3; ++kk)
#pragma unroll
            for (int ni = 0; ni < 4; ++ni)
                bf[kk][ni] = *reinterpret_cast<const short8*>(bbase[ni] + (size_t)ks * OUT_FEATS * IN_FEATS + kk * 32);
#pragma unroll
        for (int kk = 0; kk < 3; ++kk) {
            short8 af[4];
#pragma unroll
            for (int mi = 0; mi < 4; ++mi)
                af[mi] = *reinterpret_cast<const short8*>(abase[mi] + ks * IN_FEATS + kk * 32);
#pragma unroll
            for (int mi = 0; mi < 4; ++mi)
#pragma unroll
                for (int ni = 0; ni < 4; ++ni)
                    acc[mi][ni] = __builtin_amdgcn_mfma_f32_16x16x32_bf16(af[mi], bf[kk][ni], acc[mi][ni], 0, 0, 0);
        }
    }

#pragma unroll
    for (int mi = 0; mi < 4; ++mi) {
#pragma unroll
        for (int r = 0; r < 4; ++r) {
            int m = m0 + wm * 64 + mi * 16 + (lane >> 4) * 4 + r;
            if (m < N_NODES) {
                float4 c4 = *reinterpret_cast<const float4*>(&counts[m * 4]);
#pragma unroll
                for (int ni = 0; ni < 4; ++ni) {
                    int n = wn * 64 + ni * 16 + (lane & 15);
                    float bias = c4.x * b[n] + c4.y * b[OUT_FEATS + n] +
                                 c4.z * b[2 * OUT_FEATS + n] + c4.w * b[3 * OUT_FEATS + n];
                    out[(size_t)m * OUT_FEATS + n] = acc[mi][ni][r] + bias;
                }
            }
        }
    }
}

// ---------------------------------------------------------------------------
// Fallback (ws too small): direct per-(edge, j) dot product with atomics.
// ---------------------------------------------------------------------------
__global__ __launch_bounds__(256) void edge_direct(const float* __restrict__ feat,
                                                   const int* __restrict__ etypes,
                                                   const int* __restrict__ src,
                                                   const int* __restrict__ dst,
                                                   const float* __restrict__ W,
                                                   const float* __restrict__ b,
                                                   float* __restrict__ out) {
    int gid = blockIdx.x * 256 + threadIdx.x;
    int e = gid >> 7;
    int j = gid & 127;
    if (e >= N_EDGES) return;
    int et = etypes[e];
    int s = src[e];
    int d = dst[e];
    const float* f = feat + (size_t)s * IN_FEATS;
    const float* w = W + ((size_t)et * OUT_FEATS + j) * OUT_FEATS;
    float acc = b[et * OUT_FEATS + j];
    for (int k = 0; k < IN_FEATS; ++k) acc += f[k] * w[k];
    atomicAdd(&out[(size_t)d * OUT_FEATS + j], acc);
}

extern "C" void kernel_launch(void* const* d_in, const int* in_sizes, int n_in,
                              void* d_out, int out_size, void* d_ws, size_t ws_size,
                              hipStream_t stream) {
    const float* feat  = (const float*)d_in[0];
    const int*   etyps = (const int*)d_in[1];
    const int*   src   = (const int*)d_in[2];
    const int*   dst   = (const int*)d_in[3];
    const float* W     = (const float*)d_in[4];
    const float* b     = (const float*)d_in[5];
    float* out = (float*)d_out;

    const size_t off_scat   = 0;                                        // 38,400,000
    const size_t off_counts = off_scat + (size_t)N_NODES * KCAT * 2;    // +800,000
    const size_t off_deg    = off_counts + (size_t)N_NODES * 4 * 4;     // +200,000
    const size_t off_pos    = off_deg + (size_t)N_NODES * 4;            // +200,000
    const size_t off_rank   = off_pos + (size_t)N_NODES * 4;            // +2,000,000
    const size_t off_packed = off_rank + (size_t)N_EDGES * 4;           // +2,000,000
    const size_t off_bsum   = off_packed + (size_t)N_EDGES * 4;
    const size_t off_wb     = off_bsum + 1024;                          // +98,304
    const size_t need = off_wb + (size_t)512 * IN_FEATS * 2;

    if (ws_size >= need) {
        char* ws = (char*)d_ws;
        __hip_bfloat16* Scat = (__hip_bfloat16*)(ws + off_scat);
        unsigned* Scat_u32 = (unsigned*)(ws + off_scat);
        float* counts = (float*)(ws + off_counts);
        int* deg    = (int*)(ws + off_deg);
        int* pos    = (int*)(ws + off_pos);
        int* rank   = (int*)(ws + off_rank);
        int* packed = (int*)(ws + off_packed);
        int* bsum   = (int*)(ws + off_bsum);
        unsigned* Wb_u32 = (unsigned*)(ws + off_wb);
        short* Wb = (short*)(ws + off_wb);

        const int nScanBlocks = (N_NODES + 255) / 256;  // 196
        const int nEdgeBlocks = (N_EDGES + 255) / 256;  // 1954

        k_init<<<nScanBlocks, 256, 0, stream>>>(deg, W, Wb_u32);
        k_hist<<<nEdgeBlocks, 256, 0, stream>>>(dst, deg, rank);
        k_scan1<<<nScanBlocks, 256, 0, stream>>>(deg, N_NODES, pos, bsum);
        k_scan3<<<nScanBlocks, 256, 0, stream>>>(pos, bsum, N_NODES);
        k_bin<<<nEdgeBlocks, 256, 0, stream>>>(dst, src, etyps, pos, rank, packed);
        k_agg<<<N_NODES, 64, 0, stream>>>((const float2*)feat, pos, deg, packed, Scat_u32, counts);
        k_gemm<<<(N_NODES + 127) / 128, 256, 0, stream>>>(Scat, Wb, b, counts, out);
    } else {
        hipMemsetAsync(d_out, 0, (size_t)out_size * sizeof(float), stream);
        int nthreads = N_EDGES * OUT_FEATS;
        edge_direct<<<nthreads / 256, 256, 0, stream>>>(feat, etyps, src, dst, W, b, out);
    }
}

// Round 10
// 99.265 us; speedup vs baseline: 1.1695x; 1.0838x over previous
//
#include <hip/hip_runtime.h>
#include <hip/hip_bf16.h>

#define N_NODES 50000
#define N_EDGES 500000
#define IN_FEATS 96
#define OUT_FEATS 128
#define N_ETYPES 4
#define KCAT (N_ETYPES * IN_FEATS)  // 384

typedef __attribute__((ext_vector_type(8))) short short8;
typedef __attribute__((ext_vector_type(4))) float f32x4;

static __device__ inline short f2bf_bits(float f) {
    __hip_bfloat16 h = __float2bfloat16(f);
    return *reinterpret_cast<short*>(&h);
}
static __device__ inline unsigned pack2bf(float lo, float hi) {
    unsigned l = (unsigned short)f2bf_bits(lo);
    unsigned h = (unsigned short)f2bf_bits(hi);
    return l | (h << 16);
}

// ---------------------------------------------------------------------------
// k_init: zero deg[] AND pre-convert W (f32 [4][128][128], first 96 cols) to
// bf16 Wb [4*128][96] (stored as u32 pairs).
// ---------------------------------------------------------------------------
__global__ __launch_bounds__(256) void k_init(int* __restrict__ deg,
                                              const float* __restrict__ W,
                                              unsigned* __restrict__ Wb_u32) {
    int g = blockIdx.x * 256 + threadIdx.x;
    if (g < N_NODES) deg[g] = 0;
    if (g < 512 * 48) {
        int row = g / 48, pair = g % 48;
        float lo = W[(size_t)row * OUT_FEATS + pair * 2];
        float hi = W[(size_t)row * OUT_FEATS + pair * 2 + 1];
        Wb_u32[g] = pack2bf(lo, hi);
    }
}

// ---------------------------------------------------------------------------
// k_hist: degree histogram + per-edge rank
// ---------------------------------------------------------------------------
__global__ __launch_bounds__(256) void k_hist(const int* __restrict__ dst,
                                              int* __restrict__ deg,
                                              int* __restrict__ rank) {
    int e = blockIdx.x * 256 + threadIdx.x;
    if (e < N_EDGES) rank[e] = atomicAdd(&deg[dst[e]], 1);
}

__global__ __launch_bounds__(256) void k_scan1(const int* __restrict__ in, int n,
                                               int* __restrict__ out, int* __restrict__ bsum) {
    int g = blockIdx.x * 256 + threadIdx.x;
    int lane = threadIdx.x & 63, wave = threadIdx.x >> 6;
    int v = (g < n) ? in[g] : 0;
    int orig = v;
    for (int off = 1; off < 64; off <<= 1) {
        int u = __shfl_up(v, off);
        if (lane >= off) v += u;
    }
    __shared__ int wsum[4];
    if (lane == 63) wsum[wave] = v;
    __syncthreads();
    if (threadIdx.x == 0) {
        int s = 0;
        for (int w = 0; w < 4; ++w) { int t = wsum[w]; wsum[w] = s; s += t; }
        bsum[blockIdx.x] = s;
    }
    __syncthreads();
    int excl = v - orig + wsum[wave];
    if (g < n) out[g] = excl;
}

// k_scan3: each block computes its own prefix over bsum (196 ints) then adds.
__global__ __launch_bounds__(256) void k_scan3(int* __restrict__ pos, const int* __restrict__ bsum, int n) {
    const int b = blockIdx.x;
    const int t = threadIdx.x;
    const int lane = t & 63, wave = t >> 6;
    __shared__ int ws[4];
    int v = (t < b) ? bsum[t] : 0;   // b <= 195 < 256
#pragma unroll
    for (int off = 32; off > 0; off >>= 1) v += __shfl_down(v, off);
    if (lane == 0) ws[wave] = v;
    __syncthreads();
    if (t == 0) ws[0] = ws[0] + ws[1] + ws[2] + ws[3];
    __syncthreads();
    int prefix = ws[0];
    int g = b * 256 + t;
    if (g < n) pos[g] += prefix;
}

// k_bin: atomic-free scatter using precomputed rank
__global__ __launch_bounds__(256) void k_bin(const int* __restrict__ dst, const int* __restrict__ src,
                                             const int* __restrict__ etypes,
                                             const int* __restrict__ pos, const int* __restrict__ rank,
                                             int* __restrict__ packed) {
    int e = blockIdx.x * 256 + threadIdx.x;
    if (e < N_EDGES) {
        int slot = pos[dst[e]] + rank[e];
        packed[slot] = src[e] | (etypes[e] << 16);  // src < 65536, et < 4
    }
}

// ---------------------------------------------------------------------------
// Per-node aggregation (r5-proven form): 1 wave per node, float2 lanes,
// 4-deep unrolled gathers for ILP. Scat[d][et*96+k] bf16; counts f32.
// ---------------------------------------------------------------------------
__global__ __launch_bounds__(64) void k_agg(const float2* __restrict__ feat2,
                                            const int* __restrict__ pos, const int* __restrict__ deg,
                                            const int* __restrict__ packed,
                                            unsigned* __restrict__ Scat_u32,
                                            float* __restrict__ counts) {
    const int d = blockIdx.x;
    const int lane = threadIdx.x;
    const bool act = lane < 48;
    const int start = pos[d], cnt = deg[d];

    float2 a0 = {0.f, 0.f}, a1 = {0.f, 0.f}, a2 = {0.f, 0.f}, a3 = {0.f, 0.f};
    int c0 = 0, c1 = 0, c2 = 0, c3 = 0;
    const float2 zero = {0.f, 0.f};

    int i = 0;
    for (; i + 4 <= cnt; i += 4) {
        int p0 = packed[start + i + 0];
        int p1 = packed[start + i + 1];
        int p2 = packed[start + i + 2];
        int p3 = packed[start + i + 3];
        float2 v0 = act ? feat2[(size_t)(p0 & 0xFFFF) * 48 + lane] : zero;
        float2 v1 = act ? feat2[(size_t)(p1 & 0xFFFF) * 48 + lane] : zero;
        float2 v2 = act ? feat2[(size_t)(p2 & 0xFFFF) * 48 + lane] : zero;
        float2 v3 = act ? feat2[(size_t)(p3 & 0xFFFF) * 48 + lane] : zero;
        int e0 = p0 >> 16, e1 = p1 >> 16, e2 = p2 >> 16, e3 = p3 >> 16;
        if (e0 == 0) { a0.x += v0.x; a0.y += v0.y; ++c0; }
        else if (e0 == 1) { a1.x += v0.x; a1.y += v0.y; ++c1; }
        else if (e0 == 2) { a2.x += v0.x; a2.y += v0.y; ++c2; }
        else              { a3.x += v0.x; a3.y += v0.y; ++c3; }
        if (e1 == 0) { a0.x += v1.x; a0.y += v1.y; ++c0; }
        else if (e1 == 1) { a1.x += v1.x; a1.y += v1.y; ++c1; }
        else if (e1 == 2) { a2.x += v1.x; a2.y += v1.y; ++c2; }
        else              { a3.x += v1.x; a3.y += v1.y; ++c3; }
        if (e2 == 0) { a0.x += v2.x; a0.y += v2.y; ++c0; }
        else if (e2 == 1) { a1.x += v2.x; a1.y += v2.y; ++c1; }
        else if (e2 == 2) { a2.x += v2.x; a2.y += v2.y; ++c2; }
        else              { a3.x += v2.x; a3.y += v2.y; ++c3; }
        if (e3 == 0) { a0.x += v3.x; a0.y += v3.y; ++c0; }
        else if (e3 == 1) { a1.x += v3.x; a1.y += v3.y; ++c1; }
        else if (e3 == 2) { a2.x += v3.x; a2.y += v3.y; ++c2; }
        else              { a3.x += v3.x; a3.y += v3.y; ++c3; }
    }
    for (; i < cnt; ++i) {
        int p = packed[start + i];
        float2 v = act ? feat2[(size_t)(p & 0xFFFF) * 48 + lane] : zero;
        int e = p >> 16;
        if (e == 0) { a0.x += v.x; a0.y += v.y; ++c0; }
        else if (e == 1) { a1.x += v.x; a1.y += v.y; ++c1; }
        else if (e == 2) { a2.x += v.x; a2.y += v.y; ++c2; }
        else              { a3.x += v.x; a3.y += v.y; ++c3; }
    }

    if (act) {
        size_t base = (size_t)d * (KCAT / 2) + lane;  // u32 row stride 192
        Scat_u32[base]       = pack2bf(a0.x, a0.y);
        Scat_u32[base + 48]  = pack2bf(a1.x, a1.y);
        Scat_u32[base + 96]  = pack2bf(a2.x, a2.y);
        Scat_u32[base + 144] = pack2bf(a3.x, a3.y);
    }
    if (lane < 4) counts[d * 4 + lane] = (float)(lane == 0 ? c0 : lane == 1 ? c1 : lane == 2 ? c2 : c3);
}

// ---------------------------------------------------------------------------
// MFMA GEMM (r5-proven LDS-staged form): out[m][n] = Scat[m][:] . Wb[n][:] + bias
// Block 128x128, 4 waves (2x2), K-step 96 (== one etype per step).
// LDT=104 padding -> 2-way bank aliasing on frag reads (free per m136).
// ---------------------------------------------------------------------------
#define LDT 104  // padded LDS row (bf16 elems)

__global__ __launch_bounds__(256) void k_gemm(const __hip_bfloat16* __restrict__ Scat,
                                              const short* __restrict__ Wb,
                                              const float* __restrict__ b,
                                              const float* __restrict__ counts,
                                              float* __restrict__ out) {
    __shared__ __align__(16) __hip_bfloat16 As[128][LDT];
    __shared__ __align__(16) __hip_bfloat16 Bs[128][LDT];
    const int m0 = blockIdx.x * 128;
    const int tid = threadIdx.x, lane = tid & 63, wave = tid >> 6;
    const int wm = wave >> 1, wn = wave & 1;

    f32x4 acc[4][4];
#pragma unroll
    for (int i = 0; i < 4; ++i)
#pragma unroll
        for (int jj = 0; jj < 4; ++jj) acc[i][jj] = (f32x4){0.f, 0.f, 0.f, 0.f};

    for (int ks = 0; ks < 4; ++ks) {  // ks == etype
#pragma unroll
        for (int it = 0; it < 6; ++it) {
            int idx = tid + it * 256;          // 0..1535
            int row = idx / 12, c8 = idx % 12;
            int gm = m0 + row;
            if (gm > N_NODES - 1) gm = N_NODES - 1;
            short8 v = *reinterpret_cast<const short8*>(&Scat[(size_t)gm * KCAT + ks * IN_FEATS + c8 * 8]);
            *reinterpret_cast<short8*>(&As[row][c8 * 8]) = v;
        }
#pragma unroll
        for (int it = 0; it < 6; ++it) {
            int idx = tid + it * 256;          // 0..1535
            int row = idx / 12, c8 = idx % 12;
            short8 v = *reinterpret_cast<const short8*>(&Wb[((size_t)ks * OUT_FEATS + row) * IN_FEATS + c8 * 8]);
            *reinterpret_cast<short8*>(&Bs[row][c8 * 8]) = v;
        }
        __syncthreads();
#pragma unroll
        for (int kk = 0; kk < 3; ++kk) {
            short8 af[4], bf[4];
#pragma unroll
            for (int mi = 0; mi < 4; ++mi)
                af[mi] = *reinterpret_cast<const short8*>(&As[wm * 64 + mi * 16 + (lane & 15)][kk * 32 + (lane >> 4) * 8]);
#pragma unroll
            for (int ni = 0; ni < 4; ++ni)
                bf[ni] = *reinterpret_cast<const short8*>(&Bs[wn * 64 + ni * 16 + (lane & 15)][kk * 32 + (lane >> 4) * 8]);
#pragma unroll
            for (int mi = 0; mi < 4; ++mi)
#pragma unroll
                for (int ni = 0; ni < 4; ++ni)
                    acc[mi][ni] = __builtin_amdgcn_mfma_f32_16x16x32_bf16(af[mi], bf[ni], acc[mi][ni], 0, 0, 0);
        }
        __syncthreads();
    }

#pragma unroll
    for (int mi = 0; mi < 4; ++mi) {
#pragma unroll
        for (int r = 0; r < 4; ++r) {
            int m = m0 + wm * 64 + mi * 16 + (lane >> 4) * 4 + r;
            if (m < N_NODES) {
                float4 c4 = *reinterpret_cast<const float4*>(&counts[m * 4]);
#pragma unroll
                for (int ni = 0; ni < 4; ++ni) {
                    int n = wn * 64 + ni * 16 + (lane & 15);
                    float bias = c4.x * b[n] + c4.y * b[OUT_FEATS + n] +
                                 c4.z * b[2 * OUT_FEATS + n] + c4.w * b[3 * OUT_FEATS + n];
                    out[(size_t)m * OUT_FEATS + n] = acc[mi][ni][r] + bias;
                }
            }
        }
    }
}

// ---------------------------------------------------------------------------
// Fallback (ws too small): direct per-(edge, j) dot product with atomics.
// ---------------------------------------------------------------------------
__global__ __launch_bounds__(256) void edge_direct(const float* __restrict__ feat,
                                                   const int* __restrict__ etypes,
                                                   const int* __restrict__ src,
                                                   const int* __restrict__ dst,
                                                   const float* __restrict__ W,
                                                   const float* __restrict__ b,
                                                   float* __restrict__ out) {
    int gid = blockIdx.x * 256 + threadIdx.x;
    int e = gid >> 7;
    int j = gid & 127;
    if (e >= N_EDGES) return;
    int et = etypes[e];
    int s = src[e];
    int d = dst[e];
    const float* f = feat + (size_t)s * IN_FEATS;
    const float* w = W + ((size_t)et * OUT_FEATS + j) * OUT_FEATS;
    float acc = b[et * OUT_FEATS + j];
    for (int k = 0; k < IN_FEATS; ++k) acc += f[k] * w[k];
    atomicAdd(&out[(size_t)d * OUT_FEATS + j], acc);
}

extern "C" void kernel_launch(void* const* d_in, const int* in_sizes, int n_in,
                              void* d_out, int out_size, void* d_ws, size_t ws_size,
                              hipStream_t stream) {
    const float* feat  = (const float*)d_in[0];
    const int*   etyps = (const int*)d_in[1];
    const int*   src   = (const int*)d_in[2];
    const int*   dst   = (const int*)d_in[3];
    const float* W     = (const float*)d_in[4];
    const float* b     = (const float*)d_in[5];
    float* out = (float*)d_out;

    const size_t off_scat   = 0;                                        // 38,400,000
    const size_t off_counts = off_scat + (size_t)N_NODES * KCAT * 2;    // +800,000
    const size_t off_deg    = off_counts + (size_t)N_NODES * 4 * 4;     // +200,000
    const size_t off_pos    = off_deg + (size_t)N_NODES * 4;            // +200,000
    const size_t off_rank   = off_pos + (size_t)N_NODES * 4;            // +2,000,000
    const size_t off_packed = off_rank + (size_t)N_EDGES * 4;           // +2,000,000
    const size_t off_bsum   = off_packed + (size_t)N_EDGES * 4;
    const size_t off_wb     = off_bsum + 1024;                          // +98,304
    const size_t need = off_wb + (size_t)512 * IN_FEATS * 2;

    if (ws_size >= need) {
        char* ws = (char*)d_ws;
        __hip_bfloat16* Scat = (__hip_bfloat16*)(ws + off_scat);
        unsigned* Scat_u32 = (unsigned*)(ws + off_scat);
        float* counts = (float*)(ws + off_counts);
        int* deg    = (int*)(ws + off_deg);
        int* pos    = (int*)(ws + off_pos);
        int* rank   = (int*)(ws + off_rank);
        int* packed = (int*)(ws + off_packed);
        int* bsum   = (int*)(ws + off_bsum);
        unsigned* Wb_u32 = (unsigned*)(ws + off_wb);
        short* Wb = (short*)(ws + off_wb);

        const int nScanBlocks = (N_NODES + 255) / 256;  // 196
        const int nEdgeBlocks = (N_EDGES + 255) / 256;  // 1954

        k_init<<<nScanBlocks, 256, 0, stream>>>(deg, W, Wb_u32);
        k_hist<<<nEdgeBlocks, 256, 0, stream>>>(dst, deg, rank);
        k_scan1<<<nScanBlocks, 256, 0, stream>>>(deg, N_NODES, pos, bsum);
        k_scan3<<<nScanBlocks, 256, 0, stream>>>(pos, bsum, N_NODES);
        k_bin<<<nEdgeBlocks, 256, 0, stream>>>(dst, src, etyps, pos, rank, packed);
        k_agg<<<N_NODES, 64, 0, stream>>>((const float2*)feat, pos, deg, packed, Scat_u32, counts);
        k_gemm<<<(N_NODES + 127) / 128, 256, 0, stream>>>(Scat, Wb, b, counts, out);
    } else {
        hipMemsetAsync(d_out, 0, (size_t)out_size * sizeof(float), stream);
        int nthreads = N_EDGES * OUT_FEATS;
        edge_direct<<<nthreads / 256, 256, 0, stream>>>(feat, etyps, src, dst, W, b, out);
    }
}

// Round 11
// 98.867 us; speedup vs baseline: 1.1742x; 1.0040x over previous
//
#include <hip/hip_runtime.h>
#include <hip/hip_bf16.h>

#define N_NODES 50000
#define N_EDGES 500000
#define IN_FEATS 96
#define OUT_FEATS 128
#define N_ETYPES 4
#define KCAT (N_ETYPES * IN_FEATS)  // 384

typedef __attribute__((ext_vector_type(8))) short short8;
typedef __attribute__((ext_vector_type(4))) float f32x4;

static __device__ inline short f2bf_bits(float f) {
    __hip_bfloat16 h = __float2bfloat16(f);
    return *reinterpret_cast<short*>(&h);
}
static __device__ inline unsigned pack2bf(float lo, float hi) {
    unsigned l = (unsigned short)f2bf_bits(lo);
    unsigned h = (unsigned short)f2bf_bits(hi);
    return l | (h << 16);
}

// ---------------------------------------------------------------------------
// k_init: zero deg[] AND pre-convert W (f32 [4][128][128], first 96 cols) to
// bf16 Wb [4*128][96] (stored as u32 pairs).
// ---------------------------------------------------------------------------
__global__ __launch_bounds__(256) void k_init(int* __restrict__ deg,
                                              const float* __restrict__ W,
                                              unsigned* __restrict__ Wb_u32) {
    int g = blockIdx.x * 256 + threadIdx.x;
    if (g < N_NODES) deg[g] = 0;
    if (g < 512 * 48) {
        int row = g / 48, pair = g % 48;
        float lo = W[(size_t)row * OUT_FEATS + pair * 2];
        float hi = W[(size_t)row * OUT_FEATS + pair * 2 + 1];
        Wb_u32[g] = pack2bf(lo, hi);
    }
}

// ---------------------------------------------------------------------------
// k_hist: degree histogram + per-edge rank
// ---------------------------------------------------------------------------
__global__ __launch_bounds__(256) void k_hist(const int* __restrict__ dst,
                                              int* __restrict__ deg,
                                              int* __restrict__ rank) {
    int e = blockIdx.x * 256 + threadIdx.x;
    if (e < N_EDGES) rank[e] = atomicAdd(&deg[dst[e]], 1);
}

__global__ __launch_bounds__(256) void k_scan1(const int* __restrict__ in, int n,
                                               int* __restrict__ out, int* __restrict__ bsum) {
    int g = blockIdx.x * 256 + threadIdx.x;
    int lane = threadIdx.x & 63, wave = threadIdx.x >> 6;
    int v = (g < n) ? in[g] : 0;
    int orig = v;
    for (int off = 1; off < 64; off <<= 1) {
        int u = __shfl_up(v, off);
        if (lane >= off) v += u;
    }
    __shared__ int wsum[4];
    if (lane == 63) wsum[wave] = v;
    __syncthreads();
    if (threadIdx.x == 0) {
        int s = 0;
        for (int w = 0; w < 4; ++w) { int t = wsum[w]; wsum[w] = s; s += t; }
        bsum[blockIdx.x] = s;
    }
    __syncthreads();
    int excl = v - orig + wsum[wave];
    if (g < n) out[g] = excl;
}

// k_scan3: each block computes its own prefix over bsum (196 ints) then adds.
__global__ __launch_bounds__(256) void k_scan3(int* __restrict__ pos, const int* __restrict__ bsum, int n) {
    const int b = blockIdx.x;
    const int t = threadIdx.x;
    const int lane = t & 63, wave = t >> 6;
    __shared__ int ws[4];
    int v = (t < b) ? bsum[t] : 0;   // b <= 195 < 256
#pragma unroll
    for (int off = 32; off > 0; off >>= 1) v += __shfl_down(v, off);
    if (lane == 0) ws[wave] = v;
    __syncthreads();
    if (t == 0) ws[0] = ws[0] + ws[1] + ws[2] + ws[3];
    __syncthreads();
    int prefix = ws[0];
    int g = b * 256 + t;
    if (g < n) pos[g] += prefix;
}

// k_bin: atomic-free scatter using precomputed rank
__global__ __launch_bounds__(256) void k_bin(const int* __restrict__ dst, const int* __restrict__ src,
                                             const int* __restrict__ etypes,
                                             const int* __restrict__ pos, const int* __restrict__ rank,
                                             int* __restrict__ packed) {
    int e = blockIdx.x * 256 + threadIdx.x;
    if (e < N_EDGES) {
        int slot = pos[dst[e]] + rank[e];
        packed[slot] = src[e] | (etypes[e] << 16);  // src < 65536, et < 4
    }
}

// ---------------------------------------------------------------------------
// Per-node aggregation (r5-proven form): 1 wave per node, float2 lanes,
// 4-deep unrolled gathers for ILP. Scat[d][et*96+k] bf16; counts f32.
// ---------------------------------------------------------------------------
__global__ __launch_bounds__(64) void k_agg(const float2* __restrict__ feat2,
                                            const int* __restrict__ pos, const int* __restrict__ deg,
                                            const int* __restrict__ packed,
                                            unsigned* __restrict__ Scat_u32,
                                            float* __restrict__ counts) {
    const int d = blockIdx.x;
    const int lane = threadIdx.x;
    const bool act = lane < 48;
    const int start = pos[d], cnt = deg[d];

    float2 a0 = {0.f, 0.f}, a1 = {0.f, 0.f}, a2 = {0.f, 0.f}, a3 = {0.f, 0.f};
    int c0 = 0, c1 = 0, c2 = 0, c3 = 0;
    const float2 zero = {0.f, 0.f};

    int i = 0;
    for (; i + 4 <= cnt; i += 4) {
        int p0 = packed[start + i + 0];
        int p1 = packed[start + i + 1];
        int p2 = packed[start + i + 2];
        int p3 = packed[start + i + 3];
        float2 v0 = act ? feat2[(size_t)(p0 & 0xFFFF) * 48 + lane] : zero;
        float2 v1 = act ? feat2[(size_t)(p1 & 0xFFFF) * 48 + lane] : zero;
        float2 v2 = act ? feat2[(size_t)(p2 & 0xFFFF) * 48 + lane] : zero;
        float2 v3 = act ? feat2[(size_t)(p3 & 0xFFFF) * 48 + lane] : zero;
        int e0 = p0 >> 16, e1 = p1 >> 16, e2 = p2 >> 16, e3 = p3 >> 16;
        if (e0 == 0) { a0.x += v0.x; a0.y += v0.y; ++c0; }
        else if (e0 == 1) { a1.x += v0.x; a1.y += v0.y; ++c1; }
        else if (e0 == 2) { a2.x += v0.x; a2.y += v0.y; ++c2; }
        else              { a3.x += v0.x; a3.y += v0.y; ++c3; }
        if (e1 == 0) { a0.x += v1.x; a0.y += v1.y; ++c0; }
        else if (e1 == 1) { a1.x += v1.x; a1.y += v1.y; ++c1; }
        else if (e1 == 2) { a2.x += v1.x; a2.y += v1.y; ++c2; }
        else              { a3.x += v1.x; a3.y += v1.y; ++c3; }
        if (e2 == 0) { a0.x += v2.x; a0.y += v2.y; ++c0; }
        else if (e2 == 1) { a1.x += v2.x; a1.y += v2.y; ++c1; }
        else if (e2 == 2) { a2.x += v2.x; a2.y += v2.y; ++c2; }
        else              { a3.x += v2.x; a3.y += v2.y; ++c3; }
        if (e3 == 0) { a0.x += v3.x; a0.y += v3.y; ++c0; }
        else if (e3 == 1) { a1.x += v3.x; a1.y += v3.y; ++c1; }
        else if (e3 == 2) { a2.x += v3.x; a2.y += v3.y; ++c2; }
        else              { a3.x += v3.x; a3.y += v3.y; ++c3; }
    }
    for (; i < cnt; ++i) {
        int p = packed[start + i];
        float2 v = act ? feat2[(size_t)(p & 0xFFFF) * 48 + lane] : zero;
        int e = p >> 16;
        if (e == 0) { a0.x += v.x; a0.y += v.y; ++c0; }
        else if (e == 1) { a1.x += v.x; a1.y += v.y; ++c1; }
        else if (e == 2) { a2.x += v.x; a2.y += v.y; ++c2; }
        else              { a3.x += v.x; a3.y += v.y; ++c3; }
    }

    if (act) {
        size_t base = (size_t)d * (KCAT / 2) + lane;  // u32 row stride 192
        Scat_u32[base]       = pack2bf(a0.x, a0.y);
        Scat_u32[base + 48]  = pack2bf(a1.x, a1.y);
        Scat_u32[base + 96]  = pack2bf(a2.x, a2.y);
        Scat_u32[base + 144] = pack2bf(a3.x, a3.y);
    }
    if (lane < 4) counts[d * 4 + lane] = (float)(lane == 0 ? c0 : lane == 1 ? c1 : lane == 2 ? c2 : c3);
}

// ---------------------------------------------------------------------------
// MFMA GEMM: 64x128 tile per block (782 blocks -> ~3 blocks/CU, small tail;
// was 391 @ 1.5/CU with a 50%-idle tail wave). 4 waves split N into 4x32.
// Same verified fragment mapping; LDT=104 keeps frag reads ~conflict-free.
// ---------------------------------------------------------------------------
#define LDT 104  // padded LDS row (bf16 elems)

__global__ __launch_bounds__(256) void k_gemm(const __hip_bfloat16* __restrict__ Scat,
                                              const short* __restrict__ Wb,
                                              const float* __restrict__ b,
                                              const float* __restrict__ counts,
                                              float* __restrict__ out) {
    __shared__ __align__(16) __hip_bfloat16 As[64][LDT];
    __shared__ __align__(16) __hip_bfloat16 Bs[128][LDT];
    const int m0 = blockIdx.x * 64;
    const int tid = threadIdx.x, lane = tid & 63, wave = tid >> 6;
    const int wn = wave;  // N split: wave covers cols [wn*32, wn*32+32)

    f32x4 acc[4][2];
#pragma unroll
    for (int i = 0; i < 4; ++i)
#pragma unroll
        for (int jj = 0; jj < 2; ++jj) acc[i][jj] = (f32x4){0.f, 0.f, 0.f, 0.f};

    for (int ks = 0; ks < 4; ++ks) {  // ks == etype
        // stage A: 64 rows x 96 bf16 = 768 short8 -> 3 iters
#pragma unroll
        for (int it = 0; it < 3; ++it) {
            int idx = tid + it * 256;          // 0..767
            int row = idx / 12, c8 = idx % 12;
            int gm = m0 + row;
            if (gm > N_NODES - 1) gm = N_NODES - 1;
            short8 v = *reinterpret_cast<const short8*>(&Scat[(size_t)gm * KCAT + ks * IN_FEATS + c8 * 8]);
            *reinterpret_cast<short8*>(&As[row][c8 * 8]) = v;
        }
        // stage B: 128 rows x 96 bf16 = 1536 short8 -> 6 iters
#pragma unroll
        for (int it = 0; it < 6; ++it) {
            int idx = tid + it * 256;          // 0..1535
            int row = idx / 12, c8 = idx % 12;
            short8 v = *reinterpret_cast<const short8*>(&Wb[((size_t)ks * OUT_FEATS + row) * IN_FEATS + c8 * 8]);
            *reinterpret_cast<short8*>(&Bs[row][c8 * 8]) = v;
        }
        __syncthreads();
#pragma unroll
        for (int kk = 0; kk < 3; ++kk) {
            short8 af[4], bf[2];
#pragma unroll
            for (int mi = 0; mi < 4; ++mi)
                af[mi] = *reinterpret_cast<const short8*>(&As[mi * 16 + (lane & 15)][kk * 32 + (lane >> 4) * 8]);
#pragma unroll
            for (int ni = 0; ni < 2; ++ni)
                bf[ni] = *reinterpret_cast<const short8*>(&Bs[wn * 32 + ni * 16 + (lane & 15)][kk * 32 + (lane >> 4) * 8]);
#pragma unroll
            for (int mi = 0; mi < 4; ++mi)
#pragma unroll
                for (int ni = 0; ni < 2; ++ni)
                    acc[mi][ni] = __builtin_amdgcn_mfma_f32_16x16x32_bf16(af[mi], bf[ni], acc[mi][ni], 0, 0, 0);
        }
        __syncthreads();
    }

#pragma unroll
    for (int mi = 0; mi < 4; ++mi) {
#pragma unroll
        for (int r = 0; r < 4; ++r) {
            int m = m0 + mi * 16 + (lane >> 4) * 4 + r;
            if (m < N_NODES) {
                float4 c4 = *reinterpret_cast<const float4*>(&counts[m * 4]);
#pragma unroll
                for (int ni = 0; ni < 2; ++ni) {
                    int n = wn * 32 + ni * 16 + (lane & 15);
                    float bias = c4.x * b[n] + c4.y * b[OUT_FEATS + n] +
                                 c4.z * b[2 * OUT_FEATS + n] + c4.w * b[3 * OUT_FEATS + n];
                    out[(size_t)m * OUT_FEATS + n] = acc[mi][ni][r] + bias;
                }
            }
        }
    }
}

// ---------------------------------------------------------------------------
// Fallback (ws too small): direct per-(edge, j) dot product with atomics.
// ---------------------------------------------------------------------------
__global__ __launch_bounds__(256) void edge_direct(const float* __restrict__ feat,
                                                   const int* __restrict__ etypes,
                                                   const int* __restrict__ src,
                                                   const int* __restrict__ dst,
                                                   const float* __restrict__ W,
                                                   const float* __restrict__ b,
                                                   float* __restrict__ out) {
    int gid = blockIdx.x * 256 + threadIdx.x;
    int e = gid >> 7;
    int j = gid & 127;
    if (e >= N_EDGES) return;
    int et = etypes[e];
    int s = src[e];
    int d = dst[e];
    const float* f = feat + (size_t)s * IN_FEATS;
    const float* w = W + ((size_t)et * OUT_FEATS + j) * OUT_FEATS;
    float acc = b[et * OUT_FEATS + j];
    for (int k = 0; k < IN_FEATS; ++k) acc += f[k] * w[k];
    atomicAdd(&out[(size_t)d * OUT_FEATS + j], acc);
}

extern "C" void kernel_launch(void* const* d_in, const int* in_sizes, int n_in,
                              void* d_out, int out_size, void* d_ws, size_t ws_size,
                              hipStream_t stream) {
    const float* feat  = (const float*)d_in[0];
    const int*   etyps = (const int*)d_in[1];
    const int*   src   = (const int*)d_in[2];
    const int*   dst   = (const int*)d_in[3];
    const float* W     = (const float*)d_in[4];
    const float* b     = (const float*)d_in[5];
    float* out = (float*)d_out;

    const size_t off_scat   = 0;                                        // 38,400,000
    const size_t off_counts = off_scat + (size_t)N_NODES * KCAT * 2;    // +800,000
    const size_t off_deg    = off_counts + (size_t)N_NODES * 4 * 4;     // +200,000
    const size_t off_pos    = off_deg + (size_t)N_NODES * 4;            // +200,000
    const size_t off_rank   = off_pos + (size_t)N_NODES * 4;            // +2,000,000
    const size_t off_packed = off_rank + (size_t)N_EDGES * 4;           // +2,000,000
    const size_t off_bsum   = off_packed + (size_t)N_EDGES * 4;
    const size_t off_wb     = off_bsum + 1024;                          // +98,304
    const size_t need = off_wb + (size_t)512 * IN_FEATS * 2;

    if (ws_size >= need) {
        char* ws = (char*)d_ws;
        __hip_bfloat16* Scat = (__hip_bfloat16*)(ws + off_scat);
        unsigned* Scat_u32 = (unsigned*)(ws + off_scat);
        float* counts = (float*)(ws + off_counts);
        int* deg    = (int*)(ws + off_deg);
        int* pos    = (int*)(ws + off_pos);
        int* rank   = (int*)(ws + off_rank);
        int* packed = (int*)(ws + off_packed);
        int* bsum   = (int*)(ws + off_bsum);
        unsigned* Wb_u32 = (unsigned*)(ws + off_wb);
        short* Wb = (short*)(ws + off_wb);

        const int nScanBlocks = (N_NODES + 255) / 256;  // 196
        const int nEdgeBlocks = (N_EDGES + 255) / 256;  // 1954

        k_init<<<nScanBlocks, 256, 0, stream>>>(deg, W, Wb_u32);
        k_hist<<<nEdgeBlocks, 256, 0, stream>>>(dst, deg, rank);
        k_scan1<<<nScanBlocks, 256, 0, stream>>>(deg, N_NODES, pos, bsum);
        k_scan3<<<nScanBlocks, 256, 0, stream>>>(pos, bsum, N_NODES);
        k_bin<<<nEdgeBlocks, 256, 0, stream>>>(dst, src, etyps, pos, rank, packed);
        k_agg<<<N_NODES, 64, 0, stream>>>((const float2*)feat, pos, deg, packed, Scat_u32, counts);
        k_gemm<<<(N_NODES + 63) / 64, 256, 0, stream>>>(Scat, Wb, b, counts, out);
    } else {
        hipMemsetAsync(d_out, 0, (size_t)out_size * sizeof(float), stream);
        int nthreads = N_EDGES * OUT_FEATS;
        edge_direct<<<nthreads / 256, 256, 0, stream>>>(feat, etyps, src, dst, W, b, out);
    }
}